// Round 1
// baseline (313.452 us; speedup 1.0000x reference)
//
#include <hip/hip_runtime.h>
#include <hip/hip_bf16.h>

typedef __attribute__((ext_vector_type(8))) short bf16x8;
typedef __attribute__((ext_vector_type(4))) float f32x4;

#define T_TOK 1370
#define DDIM  768
#define SCV   1369   // valid tokens per slab
#define SCP   1408   // padded rows (11*128)
#define NB    8
#define NSLAB 32

__device__ __forceinline__ unsigned short f2bf(float x) {
  union { __hip_bfloat16 h; unsigned short u; } cv;
  cv.h = __float2bfloat16(x);
  return cv.u;
}

// One block per output row: mean over 3 layers -> l2norm -> bf16 store.
// dst layout: [slabs][1408][768] bf16, rows >= 1369 zeroed.
extern "C" __global__ __launch_bounds__(192) void prep_kernel(
    const float* __restrict__ src, unsigned short* __restrict__ dst,
    size_t lstride)
{
  const int row  = blockIdx.x;   // 0..1407
  const int slab = blockIdx.y;
  const int t    = threadIdx.x;  // 0..191, each owns one float4 (768 = 192*4)
  unsigned short* drow = dst + ((size_t)slab * SCP + row) * DDIM;
  if (row >= SCV) {
    ushort4 z; z.x = z.y = z.z = z.w = 0;
    reinterpret_cast<ushort4*>(drow)[t] = z;
    return;
  }
  const float* base = src + ((size_t)slab * T_TOK + row + 1) * DDIM;
  float4 a = reinterpret_cast<const float4*>(base)[t];
  float4 b = reinterpret_cast<const float4*>(base + lstride)[t];
  float4 c = reinterpret_cast<const float4*>(base + 2 * lstride)[t];
  const float k3 = 1.0f / 3.0f;
  float4 m;
  m.x = (a.x + b.x + c.x) * k3;
  m.y = (a.y + b.y + c.y) * k3;
  m.z = (a.z + b.z + c.z) * k3;
  m.w = (a.w + b.w + c.w) * k3;
  float ss = m.x * m.x + m.y * m.y + m.z * m.z + m.w * m.w;
  #pragma unroll
  for (int d = 1; d < 64; d <<= 1) ss += __shfl_xor(ss, d);
  __shared__ float wsum[3];
  if ((t & 63) == 0) wsum[t >> 6] = ss;
  __syncthreads();
  float tot = wsum[0] + wsum[1] + wsum[2];
  float rn = 1.0f / fmaxf(sqrtf(tot), 1e-12f);
  ushort4 o;
  o.x = f2bf(m.x * rn); o.y = f2bf(m.y * rn);
  o.z = f2bf(m.z * rn); o.w = f2bf(m.w * rn);
  reinterpret_cast<ushort4*>(drow)[t] = o;
}

// 128x128 tile GEMM-with-running-max. Grid (11 m-tiles, 4 chunks, 8 n).
// part layout: [32][1408] float (slab = n*4+chunk).
extern "C" __global__ __launch_bounds__(256) void simmax_kernel(
    const unsigned short* __restrict__ xq,
    const unsigned short* __restrict__ xs,
    float* __restrict__ part)
{
  const int mt  = blockIdx.x;
  const int ch  = blockIdx.y;
  const int n   = blockIdx.z;
  const int tid = threadIdx.x;
  const int lane = tid & 63;
  const int w    = tid >> 6;
  const int wr = w >> 1, wc = w & 1;
  const int l15 = lane & 15, l4 = lane >> 4;

  __shared__ unsigned short lA[128 * 64];  // 16 KB, XOR-swizzled
  __shared__ unsigned short lB[128 * 64];  // 16 KB

  const unsigned short* Aq = xq + ((size_t)n * SCP + (size_t)mt * 128) * DDIM;
  const unsigned short* Bs = xs + ((size_t)(n * 4 + ch) * SCP) * DDIM;

  float rmax[4][4];
  #pragma unroll
  for (int a = 0; a < 4; ++a)
    #pragma unroll
    for (int b = 0; b < 4; ++b) rmax[a][b] = -1e30f;

  // LDS read byte offsets: A-frag lane layout row=l&15, k=(l>>4)*8+j
  int aoff[4][2], boff[4][2];
  #pragma unroll
  for (int mf = 0; mf < 4; ++mf)
    #pragma unroll
    for (int kh = 0; kh < 2; ++kh) {
      int rowA = wr * 64 + mf * 16 + l15;
      aoff[mf][kh] = rowA * 128 + ((kh * 64 + l4 * 16) ^ ((rowA & 7) << 4));
      int rowB = wc * 64 + mf * 16 + l15;
      boff[mf][kh] = rowB * 128 + ((kh * 64 + l4 * 16) ^ ((rowB & 7) << 4));
    }

  for (int st = 0; st < 11; ++st) {
    const unsigned short* Bt = Bs + (size_t)st * 128 * DDIM;
    f32x4 acc[4][4];
    f32x4 zz = {0.f, 0.f, 0.f, 0.f};
    #pragma unroll
    for (int a = 0; a < 4; ++a)
      #pragma unroll
      for (int b = 0; b < 4; ++b) acc[a][b] = zz;

    for (int ks = 0; ks < 12; ++ks) {
      __syncthreads();
      {
        const unsigned short* gA = Aq + ks * 64;
        const unsigned short* gB = Bt + ks * 64;
        #pragma unroll
        for (int p = 0; p < 4; ++p) {
          int idx = p * 256 + tid;
          int row = idx >> 3, c = idx & 7;
          int off = (row << 7) + ((c << 4) ^ ((row & 7) << 4));
          uint4 va = *reinterpret_cast<const uint4*>(gA + (size_t)row * DDIM + c * 8);
          *reinterpret_cast<uint4*>(reinterpret_cast<char*>(lA) + off) = va;
          uint4 vb = *reinterpret_cast<const uint4*>(gB + (size_t)row * DDIM + c * 8);
          *reinterpret_cast<uint4*>(reinterpret_cast<char*>(lB) + off) = vb;
        }
      }
      __syncthreads();
      bf16x8 af[4][2], bfr[4][2];
      #pragma unroll
      for (int mf = 0; mf < 4; ++mf)
        #pragma unroll
        for (int kh = 0; kh < 2; ++kh) {
          af[mf][kh]  = *reinterpret_cast<const bf16x8*>(reinterpret_cast<const char*>(lA) + aoff[mf][kh]);
          bfr[mf][kh] = *reinterpret_cast<const bf16x8*>(reinterpret_cast<const char*>(lB) + boff[mf][kh]);
        }
      #pragma unroll
      for (int mf = 0; mf < 4; ++mf)
        #pragma unroll
        for (int nf = 0; nf < 4; ++nf)
          #pragma unroll
          for (int kh = 0; kh < 2; ++kh)
            acc[mf][nf] = __builtin_amdgcn_mfma_f32_16x16x32_bf16(
                af[mf][kh], bfr[nf][kh], acc[mf][nf], 0, 0, 0);
    }

    // fold this s-tile into running max (mask cols >= 1369)
    #pragma unroll
    for (int nf = 0; nf < 4; ++nf) {
      int col = st * 128 + wc * 64 + nf * 16 + l15;
      if (col < SCV) {
        #pragma unroll
        for (int mf = 0; mf < 4; ++mf)
          #pragma unroll
          for (int j = 0; j < 4; ++j)
            rmax[mf][j] = fmaxf(rmax[mf][j], acc[mf][nf][j]);
      }
    }
  }

  // butterfly max over the 16 col-lanes
  #pragma unroll
  for (int msk = 1; msk < 16; msk <<= 1)
    #pragma unroll
    for (int mf = 0; mf < 4; ++mf)
      #pragma unroll
      for (int j = 0; j < 4; ++j)
        rmax[mf][j] = fmaxf(rmax[mf][j], __shfl_xor(rmax[mf][j], msk));

  // combine the two col-waves via LDS, write partial
  __syncthreads();
  float* buf = reinterpret_cast<float*>(lA);
  if (l15 == 0) {
    #pragma unroll
    for (int mf = 0; mf < 4; ++mf)
      #pragma unroll
      for (int j = 0; j < 4; ++j) {
        int r = wr * 64 + mf * 16 + l4 * 4 + j;
        buf[wc * 128 + r] = rmax[mf][j];
      }
  }
  __syncthreads();
  if (tid < 128) {
    float v = fmaxf(buf[tid], buf[128 + tid]);
    part[(size_t)(n * 4 + ch) * SCP + (size_t)mt * 128 + tid] = v;
  }
}

extern "C" __global__ void finalize_kernel(const float* __restrict__ part,
                                           float* __restrict__ out) {
  int i = blockIdx.x * 256 + threadIdx.x;
  if (i >= NB * SCV) return;
  int n = i / SCV, q = i - n * SCV;
  float m = part[(size_t)(n * 4 + 0) * SCP + q];
  m = fmaxf(m, part[(size_t)(n * 4 + 1) * SCP + q]);
  m = fmaxf(m, part[(size_t)(n * 4 + 2) * SCP + q]);
  m = fmaxf(m, part[(size_t)(n * 4 + 3) * SCP + q]);
  out[i] = 1.0f - m;
}

extern "C" void kernel_launch(void* const* d_in, const int* in_sizes, int n_in,
                              void* d_out, int out_size, void* d_ws, size_t ws_size,
                              hipStream_t stream) {
  const float* q_feats = (const float*)d_in[0];  // (3, 8, 1370, 768) f32
  const float* s_feats = (const float*)d_in[1];  // (3, 32, 1370, 768) f32
  float* out = (float*)d_out;                    // (8, 1, 37, 37) f32

  char* ws = (char*)d_ws;
  const size_t xq_bytes = (size_t)NB * SCP * DDIM * 2;     // 17,301,504
  const size_t xs_bytes = (size_t)NSLAB * SCP * DDIM * 2;  // 69,206,016
  unsigned short* xq = (unsigned short*)ws;
  unsigned short* xs = (unsigned short*)(ws + xq_bytes);
  float* part        = (float*)(ws + xq_bytes + xs_bytes); // 32*1408 floats

  prep_kernel<<<dim3(SCP, NB), 192, 0, stream>>>(
      q_feats, xq, (size_t)NB * T_TOK * DDIM);
  prep_kernel<<<dim3(SCP, NSLAB), 192, 0, stream>>>(
      s_feats, xs, (size_t)NSLAB * T_TOK * DDIM);
  simmax_kernel<<<dim3(11, 4, NB), 256, 0, stream>>>(xq, xs, part);
  finalize_kernel<<<dim3((NB * SCV + 255) / 256), 256, 0, stream>>>(part, out);
}

// Round 2
// 271.650 us; speedup vs baseline: 1.1539x; 1.1539x over previous
//
#include <hip/hip_runtime.h>
#include <hip/hip_bf16.h>

typedef __attribute__((ext_vector_type(8))) short bf16x8;
typedef __attribute__((ext_vector_type(4))) float f32x4;

#define T_TOK 1370
#define DDIM  768
#define SCV   1369   // valid tokens per slab
#define SCP   1408   // padded rows (11*128)
#define NB    8
#define NSLAB 32
#define NSG   11     // s-groups per n (44 s-tiles / 4 per block)

__device__ __forceinline__ unsigned short f2bf(float x) {
  union { __hip_bfloat16 h; unsigned short u; } cv;
  cv.h = __float2bfloat16(x);
  return cv.u;
}

#define GLOAD_LDS16(g, l)                                                     \
  __builtin_amdgcn_global_load_lds(                                           \
      (const __attribute__((address_space(1))) unsigned int*)(g),             \
      (__attribute__((address_space(3))) unsigned int*)(l), 16, 0, 0)

// One block per output row: mean over 3 layers -> l2norm -> bf16 store.
// dst layout: [slabs][1408][768] bf16, rows >= 1369 zeroed.
extern "C" __global__ __launch_bounds__(192) void prep_kernel(
    const float* __restrict__ src, unsigned short* __restrict__ dst,
    size_t lstride)
{
  const int row  = blockIdx.x;   // 0..1407
  const int slab = blockIdx.y;
  const int t    = threadIdx.x;  // 0..191, each owns one float4 (768 = 192*4)
  unsigned short* drow = dst + ((size_t)slab * SCP + row) * DDIM;
  if (row >= SCV) {
    ushort4 z; z.x = z.y = z.z = z.w = 0;
    reinterpret_cast<ushort4*>(drow)[t] = z;
    return;
  }
  const float* base = src + ((size_t)slab * T_TOK + row + 1) * DDIM;
  float4 a = reinterpret_cast<const float4*>(base)[t];
  float4 b = reinterpret_cast<const float4*>(base + lstride)[t];
  float4 c = reinterpret_cast<const float4*>(base + 2 * lstride)[t];
  const float k3 = 1.0f / 3.0f;
  float4 m;
  m.x = (a.x + b.x + c.x) * k3;
  m.y = (a.y + b.y + c.y) * k3;
  m.z = (a.z + b.z + c.z) * k3;
  m.w = (a.w + b.w + c.w) * k3;
  float ss = m.x * m.x + m.y * m.y + m.z * m.z + m.w * m.w;
  #pragma unroll
  for (int d = 1; d < 64; d <<= 1) ss += __shfl_xor(ss, d);
  __shared__ float wsum[3];
  if ((t & 63) == 0) wsum[t >> 6] = ss;
  __syncthreads();
  float tot = wsum[0] + wsum[1] + wsum[2];
  float rn = 1.0f / fmaxf(sqrtf(tot), 1e-12f);
  ushort4 o;
  o.x = f2bf(m.x * rn); o.y = f2bf(m.y * rn);
  o.z = f2bf(m.z * rn); o.w = f2bf(m.w * rn);
  reinterpret_cast<ushort4*>(drow)[t] = o;
}

// 128x128 tile GEMM-with-running-max, global_load_lds staging.
// Grid (11 m-tiles, 11 s-groups, 8 n); each block does 4 s-tiles.
// part layout: [8][11][1408] float.
extern "C" __global__ __launch_bounds__(256) void simmax_kernel(
    const unsigned short* __restrict__ xq,
    const unsigned short* __restrict__ xs,
    float* __restrict__ part)
{
  const int mt  = blockIdx.x;   // 0..10
  const int sg  = blockIdx.y;   // 0..10
  const int n   = blockIdx.z;   // 0..7
  const int tid = threadIdx.x;
  const int lane = tid & 63;
  const int w    = tid >> 6;
  const int wr = w >> 1, wc = w & 1;
  const int l15 = lane & 15, l4 = lane >> 4;

  __shared__ unsigned short lA[128 * 64];  // 16 KB, XOR-swizzled (via source)
  __shared__ unsigned short lB[128 * 64];  // 16 KB

  const unsigned short* Aq = xq + ((size_t)n * SCP + (size_t)mt * 128) * DDIM;

  // staging: wave w owns 1-KB chunks w*4..w*4+3; chunk c = rows [c*8, c*8+8),
  // lane covers row c*8 + (lane>>3), 16B slot (lane&7). Global source is
  // pre-swizzled: slot ^ (row&7); LDS dest stays linear (HW: base + lane*16).
  int goff[4];
  unsigned short* ldsA[4];
  unsigned short* ldsB[4];
  #pragma unroll
  for (int i = 0; i < 4; ++i) {
    int chunk = w * 4 + i;
    int row = chunk * 8 + (lane >> 3);
    goff[i] = row * DDIM + (((lane & 7) ^ (row & 7)) << 3);
    ldsA[i] = lA + chunk * 512;
    ldsB[i] = lB + chunk * 512;
  }

  // LDS read byte offsets (swizzled): row*128 + (chunk16*16 ^ ((row&7)<<4))
  int aoff[4][2], boff[4][2];
  #pragma unroll
  for (int mf = 0; mf < 4; ++mf)
    #pragma unroll
    for (int kh = 0; kh < 2; ++kh) {
      int rowA = wr * 64 + mf * 16 + l15;
      aoff[mf][kh] = rowA * 128 + ((kh * 64 + l4 * 16) ^ ((rowA & 7) << 4));
      int rowB = wc * 64 + mf * 16 + l15;
      boff[mf][kh] = rowB * 128 + ((kh * 64 + l4 * 16) ^ ((rowB & 7) << 4));
    }

  float rmax[4][4];
  #pragma unroll
  for (int a = 0; a < 4; ++a)
    #pragma unroll
    for (int b = 0; b < 4; ++b) rmax[a][b] = -1e30f;

  for (int st4 = 0; st4 < 4; ++st4) {
    const int st   = sg * 4 + st4;       // global s-tile 0..43
    const int slab = st / 11;
    const int lt   = st - slab * 11;     // tile within slab
    const unsigned short* Bt =
        xs + ((size_t)(n * 4 + slab) * SCP + (size_t)lt * 128) * DDIM;

    f32x4 acc[4][4];
    f32x4 zz = {0.f, 0.f, 0.f, 0.f};
    #pragma unroll
    for (int a = 0; a < 4; ++a)
      #pragma unroll
      for (int b = 0; b < 4; ++b) acc[a][b] = zz;

    for (int ks = 0; ks < 12; ++ks) {
      __syncthreads();  // previous iteration's LDS reads done
      #pragma unroll
      for (int i = 0; i < 4; ++i) {
        GLOAD_LDS16(Aq + goff[i] + ks * 64, ldsA[i]);
        GLOAD_LDS16(Bt + goff[i] + ks * 64, ldsB[i]);
      }
      __syncthreads();  // vmcnt(0) drained by compiler before barrier
      bf16x8 af[4][2], bfr[4][2];
      #pragma unroll
      for (int mf = 0; mf < 4; ++mf)
        #pragma unroll
        for (int kh = 0; kh < 2; ++kh) {
          af[mf][kh]  = *reinterpret_cast<const bf16x8*>(reinterpret_cast<const char*>(lA) + aoff[mf][kh]);
          bfr[mf][kh] = *reinterpret_cast<const bf16x8*>(reinterpret_cast<const char*>(lB) + boff[mf][kh]);
        }
      #pragma unroll
      for (int mf = 0; mf < 4; ++mf)
        #pragma unroll
        for (int nf = 0; nf < 4; ++nf)
          #pragma unroll
          for (int kh = 0; kh < 2; ++kh)
            acc[mf][nf] = __builtin_amdgcn_mfma_f32_16x16x32_bf16(
                af[mf][kh], bfr[nf][kh], acc[mf][nf], 0, 0, 0);
    }

    // fold this s-tile into running max (mask cols >= 1369 within slab)
    #pragma unroll
    for (int nf = 0; nf < 4; ++nf) {
      int col = lt * 128 + wc * 64 + nf * 16 + l15;
      if (col < SCV) {
        #pragma unroll
        for (int mf = 0; mf < 4; ++mf)
          #pragma unroll
          for (int j = 0; j < 4; ++j)
            rmax[mf][j] = fmaxf(rmax[mf][j], acc[mf][nf][j]);
      }
    }
  }

  // butterfly max over the 16 col-lanes
  #pragma unroll
  for (int msk = 1; msk < 16; msk <<= 1)
    #pragma unroll
    for (int mf = 0; mf < 4; ++mf)
      #pragma unroll
      for (int j = 0; j < 4; ++j)
        rmax[mf][j] = fmaxf(rmax[mf][j], __shfl_xor(rmax[mf][j], msk));

  // combine the two col-waves via LDS, write partial
  __syncthreads();
  float* buf = reinterpret_cast<float*>(lA);
  if (l15 == 0) {
    #pragma unroll
    for (int mf = 0; mf < 4; ++mf)
      #pragma unroll
      for (int j = 0; j < 4; ++j) {
        int r = wr * 64 + mf * 16 + l4 * 4 + j;
        buf[wc * 128 + r] = rmax[mf][j];
      }
  }
  __syncthreads();
  if (tid < 128) {
    float v = fmaxf(buf[tid], buf[128 + tid]);
    part[((size_t)n * NSG + sg) * SCP + (size_t)mt * 128 + tid] = v;
  }
}

extern "C" __global__ void finalize_kernel(const float* __restrict__ part,
                                           float* __restrict__ out) {
  int i = blockIdx.x * 256 + threadIdx.x;
  if (i >= NB * SCV) return;
  int n = i / SCV, q = i - n * SCV;
  const float* p = part + (size_t)n * NSG * SCP + q;
  float m = p[0];
  #pragma unroll
  for (int g = 1; g < NSG; ++g) m = fmaxf(m, p[(size_t)g * SCP]);
  out[i] = 1.0f - m;
}

extern "C" void kernel_launch(void* const* d_in, const int* in_sizes, int n_in,
                              void* d_out, int out_size, void* d_ws, size_t ws_size,
                              hipStream_t stream) {
  const float* q_feats = (const float*)d_in[0];  // (3, 8, 1370, 768) f32
  const float* s_feats = (const float*)d_in[1];  // (3, 32, 1370, 768) f32
  float* out = (float*)d_out;                    // (8, 1, 37, 37) f32

  char* ws = (char*)d_ws;
  const size_t xq_bytes = (size_t)NB * SCP * DDIM * 2;     // 17,301,504
  const size_t xs_bytes = (size_t)NSLAB * SCP * DDIM * 2;  // 69,206,016
  unsigned short* xq = (unsigned short*)ws;
  unsigned short* xs = (unsigned short*)(ws + xq_bytes);
  float* part        = (float*)(ws + xq_bytes + xs_bytes); // 8*11*1408 floats

  prep_kernel<<<dim3(SCP, NB), 192, 0, stream>>>(
      q_feats, xq, (size_t)NB * T_TOK * DDIM);
  prep_kernel<<<dim3(SCP, NSLAB), 192, 0, stream>>>(
      s_feats, xs, (size_t)NSLAB * T_TOK * DDIM);
  simmax_kernel<<<dim3(11, NSG, NB), 256, 0, stream>>>(xq, xs, part);
  finalize_kernel<<<dim3((NB * SCV + 255) / 256), 256, 0, stream>>>(part, out);
}

// Round 3
// 271.088 us; speedup vs baseline: 1.1563x; 1.0021x over previous
//
#include <hip/hip_runtime.h>
#include <hip/hip_bf16.h>

typedef __attribute__((ext_vector_type(8))) short bf16x8;
typedef __attribute__((ext_vector_type(4))) float f32x4;

#define T_TOK 1370
#define DDIM  768
#define SCV   1369   // valid tokens per slab
#define SCP   1408   // s slab padded rows (11*128)
#define MQP   1536   // q padded rows (6*256)
#define NB    8
#define NSLAB 32
#define NST   22     // s supertiles of 256 (4*1408/256)
#define NMT   6      // m tiles of 256

#define MEMFENCE asm volatile("" ::: "memory")
#define BARRIER  do { __builtin_amdgcn_s_barrier(); MEMFENCE; } while (0)
#define VMCNT0   asm volatile("s_waitcnt vmcnt(0)" ::: "memory")

__device__ __forceinline__ unsigned short f2bf(float x) {
  union { __hip_bfloat16 h; unsigned short u; } cv;
  cv.h = __float2bfloat16(x);
  return cv.u;
}

#define GLOAD_LDS16(g, l)                                                     \
  __builtin_amdgcn_global_load_lds(                                           \
      (const __attribute__((address_space(1))) unsigned int*)(g),             \
      (__attribute__((address_space(3))) unsigned int*)(l), 16, 0, 0)

// One block per output row: mean over 3 layers -> l2norm -> bf16 store.
// dst layout: [slabs][pad][768] bf16, rows >= 1369 zeroed. pad via gridDim.x.
extern "C" __global__ __launch_bounds__(192) void prep_kernel(
    const float* __restrict__ src, unsigned short* __restrict__ dst,
    size_t lstride)
{
  const int row  = blockIdx.x;
  const int slab = blockIdx.y;
  const int t    = threadIdx.x;  // 0..191, each owns one float4 (768 = 192*4)
  unsigned short* drow = dst + ((size_t)slab * gridDim.x + row) * DDIM;
  if (row >= SCV) {
    ushort4 z; z.x = z.y = z.z = z.w = 0;
    reinterpret_cast<ushort4*>(drow)[t] = z;
    return;
  }
  const float* base = src + ((size_t)slab * T_TOK + row + 1) * DDIM;
  float4 a = reinterpret_cast<const float4*>(base)[t];
  float4 b = reinterpret_cast<const float4*>(base + lstride)[t];
  float4 c = reinterpret_cast<const float4*>(base + 2 * lstride)[t];
  const float k3 = 1.0f / 3.0f;
  float4 m;
  m.x = (a.x + b.x + c.x) * k3;
  m.y = (a.y + b.y + c.y) * k3;
  m.z = (a.z + b.z + c.z) * k3;
  m.w = (a.w + b.w + c.w) * k3;
  float ss = m.x * m.x + m.y * m.y + m.z * m.z + m.w * m.w;
  #pragma unroll
  for (int d = 1; d < 64; d <<= 1) ss += __shfl_xor(ss, d);
  __shared__ float wsum[3];
  if ((t & 63) == 0) wsum[t >> 6] = ss;
  __syncthreads();
  float tot = wsum[0] + wsum[1] + wsum[2];
  float rn = 1.0f / fmaxf(sqrtf(tot), 1e-12f);
  ushort4 o;
  o.x = f2bf(m.x * rn); o.y = f2bf(m.y * rn);
  o.z = f2bf(m.z * rn); o.w = f2bf(m.w * rn);
  reinterpret_cast<ushort4*>(drow)[t] = o;
}

#define READ_A(AF, MQ)                                                        \
  _Pragma("unroll") for (int m2 = 0; m2 < 2; ++m2)                            \
  _Pragma("unroll") for (int kh = 0; kh < 2; ++kh)                            \
    AF[m2][kh] = *reinterpret_cast<const bf16x8*>(                            \
        reinterpret_cast<const char*>(Ab) +                                   \
        (arow + ((MQ)*2 + m2) * 16) * 128 + koff[kh]);

#define DO_MFMA(AF, MQ)                                                       \
  __builtin_amdgcn_s_setprio(1);                                             \
  _Pragma("unroll") for (int m2 = 0; m2 < 2; ++m2)                            \
  _Pragma("unroll") for (int nf = 0; nf < 4; ++nf)                            \
  _Pragma("unroll") for (int kh = 0; kh < 2; ++kh)                            \
    acc[(MQ)*2 + m2][nf] = __builtin_amdgcn_mfma_f32_16x16x32_bf16(           \
        AF[m2][kh], bf[nf][kh], acc[(MQ)*2 + m2][nf], 0, 0, 0);               \
  __builtin_amdgcn_s_setprio(0);

// 256x256 tile GEMM-with-running-max, 8 waves, 4-phase K-groups,
// double-buffered LDS with group-ahead prefetch issue.
// Grid (6 m-tiles, 22 s-supertiles, 8 n). part: [8][22][1536] float.
extern "C" __global__ __launch_bounds__(512, 2) void simmax_kernel(
    const unsigned short* __restrict__ xq,
    const unsigned short* __restrict__ xs,
    float* __restrict__ part)
{
  const int mt  = blockIdx.x;   // 0..5
  const int stt = blockIdx.y;   // 0..21
  const int n   = blockIdx.z;   // 0..7
  const int tid = threadIdx.x;  // 0..511
  const int lane = tid & 63;
  const int w    = tid >> 6;    // 0..7
  const int wr   = w >> 2;      // 0..1  row half (128 rows)
  const int wcn  = w & 3;       // 0..3  col quarter (64 cols)
  const int l15 = lane & 15, l4 = lane >> 4;

  __shared__ unsigned short sA[2][256 * 64];  // 64 KB (XOR-swizzled via src)
  __shared__ unsigned short sB[2][256 * 64];  // 64 KB

  const unsigned short* gA = xq + ((size_t)n * MQP + (size_t)mt * 256) * DDIM;
  const unsigned short* gB = xs + ((size_t)n * 4 * SCP + (size_t)stt * 256) * DDIM;

  // staging: tile = 32 chunks of 1KB (8 rows each); wave stages chunks w*4..+3.
  // lane covers row c*8+(lane>>3), 16B slot (lane&7); source pre-swizzled by
  // (row&7) so linear LDS dest + XOR read = consistent involution.
  int soff[4], ldso[4];
  #pragma unroll
  for (int i = 0; i < 4; ++i) {
    int c = w * 4 + i;
    int r = c * 8 + (lane >> 3);
    soff[i] = r * DDIM + (((lane & 7) ^ (r & 7)) << 3);
    ldso[i] = c * 512;
  }

  // fragment read bases (byte offsets); row&7 == l15&7 for all frags
  const int swz = (l15 & 7) << 4;
  int koff[2];
  koff[0] = (l4 * 16) ^ swz;
  koff[1] = (64 + l4 * 16) ^ swz;
  const int arow = wr * 128 + l15;
  const int brow = wcn * 64 + l15;

  f32x4 acc[8][4];
  {
    f32x4 zz = {0.f, 0.f, 0.f, 0.f};
    #pragma unroll
    for (int a = 0; a < 8; ++a)
      #pragma unroll
      for (int b = 0; b < 4; ++b) acc[a][b] = zz;
  }

  // prologue: stage kt=0 into buffer 0, drain, sync
  #pragma unroll
  for (int i = 0; i < 4; ++i) GLOAD_LDS16(gA + soff[i], sA[0] + ldso[i]);
  #pragma unroll
  for (int i = 0; i < 4; ++i) GLOAD_LDS16(gB + soff[i], sB[0] + ldso[i]);
  VMCNT0;
  BARRIER;

  for (int kt = 0; kt < 12; ++kt) {
    const unsigned short* Ab = sA[kt & 1];
    const unsigned short* Bb = sB[kt & 1];
    unsigned short* An = sA[(kt & 1) ^ 1];
    unsigned short* Bn = sB[(kt & 1) ^ 1];
    const bool issue = (kt < 11);

    // ---- phase 1: B frags (held all group) + A mf{0,1}; issue next stages
    bf16x8 bf[4][2];
    _Pragma("unroll") for (int nf = 0; nf < 4; ++nf)
      _Pragma("unroll") for (int kh = 0; kh < 2; ++kh)
        bf[nf][kh] = *reinterpret_cast<const bf16x8*>(
            reinterpret_cast<const char*>(Bb) + (brow + nf * 16) * 128 + koff[kh]);
    bf16x8 af0[2][2];
    READ_A(af0, 0);
    if (issue) {
      const unsigned short* ga = gA + (kt + 1) * 64;
      const unsigned short* gb = gB + (kt + 1) * 64;
      #pragma unroll
      for (int i = 0; i < 4; ++i) GLOAD_LDS16(ga + soff[i], An + ldso[i]);
      #pragma unroll
      for (int i = 0; i < 4; ++i) GLOAD_LDS16(gb + soff[i], Bn + ldso[i]);
    }
    BARRIER;                       // mid
    DO_MFMA(af0, 0);
    BARRIER;                       // end ph1

    bf16x8 af1[2][2];
    READ_A(af1, 1);
    BARRIER;
    DO_MFMA(af1, 1);
    BARRIER;

    bf16x8 af2[2][2];
    READ_A(af2, 2);
    BARRIER;
    DO_MFMA(af2, 2);
    BARRIER;

    bf16x8 af3[2][2];
    READ_A(af3, 3);
    BARRIER;
    DO_MFMA(af3, 3);
    if (issue) VMCNT0;             // youngest stage is 3 phases old here
    BARRIER;                       // group boundary: buffer swap safe
  }

  // ---- epilogue: masked running max, butterfly, cross-wave combine
  float rmax[8][4];
  #pragma unroll
  for (int a = 0; a < 8; ++a)
    #pragma unroll
    for (int b = 0; b < 4; ++b) rmax[a][b] = -1e30f;

  const int colbase = stt * 256 + wcn * 64;
  #pragma unroll
  for (int nf = 0; nf < 4; ++nf) {
    int col = colbase + nf * 16 + l15;
    int within = col - (col / SCP) * SCP;
    if (within < SCV) {
      #pragma unroll
      for (int mf = 0; mf < 8; ++mf)
        #pragma unroll
        for (int j = 0; j < 4; ++j)
          rmax[mf][j] = fmaxf(rmax[mf][j], acc[mf][nf][j]);
    }
  }

  #pragma unroll
  for (int msk = 1; msk < 16; msk <<= 1)
    #pragma unroll
    for (int mf = 0; mf < 8; ++mf)
      #pragma unroll
      for (int j = 0; j < 4; ++j)
        rmax[mf][j] = fmaxf(rmax[mf][j], __shfl_xor(rmax[mf][j], msk));

  __syncthreads();
  float* buf = reinterpret_cast<float*>(&sA[0][0]);  // 4*256 floats
  if (l15 == 0) {
    #pragma unroll
    for (int mf = 0; mf < 8; ++mf)
      #pragma unroll
      for (int j = 0; j < 4; ++j)
        buf[wcn * 256 + wr * 128 + mf * 16 + l4 * 4 + j] = rmax[mf][j];
  }
  __syncthreads();
  if (tid < 256) {
    float v = fmaxf(fmaxf(buf[tid], buf[256 + tid]),
                    fmaxf(buf[512 + tid], buf[768 + tid]));
    part[((size_t)n * NST + stt) * MQP + (size_t)mt * 256 + tid] = v;
  }
}

extern "C" __global__ void finalize_kernel(const float* __restrict__ part,
                                           float* __restrict__ out) {
  int i = blockIdx.x * 256 + threadIdx.x;
  if (i >= NB * SCV) return;
  int n = i / SCV, q = i - n * SCV;
  const float* p = part + (size_t)n * NST * MQP + q;
  float m = p[0];
  #pragma unroll
  for (int g = 1; g < NST; ++g) m = fmaxf(m, p[(size_t)g * MQP]);
  out[i] = 1.0f - m;
}

extern "C" void kernel_launch(void* const* d_in, const int* in_sizes, int n_in,
                              void* d_out, int out_size, void* d_ws, size_t ws_size,
                              hipStream_t stream) {
  const float* q_feats = (const float*)d_in[0];  // (3, 8, 1370, 768) f32
  const float* s_feats = (const float*)d_in[1];  // (3, 32, 1370, 768) f32
  float* out = (float*)d_out;                    // (8, 1, 37, 37) f32

  char* ws = (char*)d_ws;
  const size_t xq_bytes = (size_t)NB * MQP * DDIM * 2;     // 18,874,368
  const size_t xs_bytes = (size_t)NSLAB * SCP * DDIM * 2;  // 69,206,016
  unsigned short* xq = (unsigned short*)ws;
  unsigned short* xs = (unsigned short*)(ws + xq_bytes);
  float* part        = (float*)(ws + xq_bytes + xs_bytes); // 8*22*1536 floats

  prep_kernel<<<dim3(MQP, NB), 192, 0, stream>>>(
      q_feats, xq, (size_t)NB * T_TOK * DDIM);
  prep_kernel<<<dim3(SCP, NSLAB), 192, 0, stream>>>(
      s_feats, xs, (size_t)NSLAB * T_TOK * DDIM);
  simmax_kernel<<<dim3(NMT, NST, NB), 512, 0, stream>>>(xq, xs, part);
  finalize_kernel<<<dim3((NB * SCV + 255) / 256), 256, 0, stream>>>(part, out);
}

// Round 4
// 256.307 us; speedup vs baseline: 1.2230x; 1.0577x over previous
//
#include <hip/hip_runtime.h>
#include <hip/hip_bf16.h>

typedef __attribute__((ext_vector_type(8))) short bf16x8;
typedef __attribute__((ext_vector_type(4))) float f32x4;

#define T_TOK 1370
#define DDIM  768
#define SCV   1369   // valid tokens per slab
#define SCP   1408   // s slab padded rows (11*128)
#define MQP   1536   // q padded rows (12*128)
#define NB    8
#define NSLAB 32
#define NST   44     // s tiles of 128 (4 slabs * 11)
#define NMT   12     // m tiles of 128

#define MEMFENCE asm volatile("" ::: "memory")
#define BARRIER  do { __builtin_amdgcn_s_barrier(); MEMFENCE; } while (0)
#define VMCNT0   asm volatile("s_waitcnt vmcnt(0)" ::: "memory")

__device__ __forceinline__ unsigned short f2bf(float x) {
  union { __hip_bfloat16 h; unsigned short u; } cv;
  cv.h = __float2bfloat16(x);
  return cv.u;
}

#define GLOAD_LDS16(g, l)                                                     \
  __builtin_amdgcn_global_load_lds(                                           \
      (const __attribute__((address_space(1))) unsigned int*)(g),             \
      (__attribute__((address_space(3))) unsigned int*)(l), 16, 0, 0)

// One block per output row: mean over 3 layers -> l2norm -> bf16 store.
// dst layout: [slabs][pad][768] bf16, rows >= 1369 zeroed. pad via gridDim.x.
extern "C" __global__ __launch_bounds__(192) void prep_kernel(
    const float* __restrict__ src, unsigned short* __restrict__ dst,
    size_t lstride)
{
  const int row  = blockIdx.x;
  const int slab = blockIdx.y;
  const int t    = threadIdx.x;  // 0..191, each owns one float4 (768 = 192*4)
  unsigned short* drow = dst + ((size_t)slab * gridDim.x + row) * DDIM;
  if (row >= SCV) {
    ushort4 z; z.x = z.y = z.z = z.w = 0;
    reinterpret_cast<ushort4*>(drow)[t] = z;
    return;
  }
  const float* base = src + ((size_t)slab * T_TOK + row + 1) * DDIM;
  float4 a = reinterpret_cast<const float4*>(base)[t];
  float4 b = reinterpret_cast<const float4*>(base + lstride)[t];
  float4 c = reinterpret_cast<const float4*>(base + 2 * lstride)[t];
  const float k3 = 1.0f / 3.0f;
  float4 m;
  m.x = (a.x + b.x + c.x) * k3;
  m.y = (a.y + b.y + c.y) * k3;
  m.z = (a.z + b.z + c.z) * k3;
  m.w = (a.w + b.w + c.w) * k3;
  float ss = m.x * m.x + m.y * m.y + m.z * m.z + m.w * m.w;
  #pragma unroll
  for (int d = 1; d < 64; d <<= 1) ss += __shfl_xor(ss, d);
  __shared__ float wsum[3];
  if ((t & 63) == 0) wsum[t >> 6] = ss;
  __syncthreads();
  float tot = wsum[0] + wsum[1] + wsum[2];
  float rn = 1.0f / fmaxf(sqrtf(tot), 1e-12f);
  ushort4 o;
  o.x = f2bf(m.x * rn); o.y = f2bf(m.y * rn);
  o.z = f2bf(m.z * rn); o.w = f2bf(m.w * rn);
  reinterpret_cast<ushort4*>(drow)[t] = o;
}

// 128x128 tile GEMM-with-running-max, double-buffered global_load_lds,
// one barrier + one drain per K-step, 2 blocks/CU, XCD-chunked swizzle.
// Logical work (mt, st, n); part: [8][44][1536] float.
extern "C" __global__ __launch_bounds__(256, 2) void simmax_kernel(
    const unsigned short* __restrict__ xq,
    const unsigned short* __restrict__ xs,
    float* __restrict__ part)
{
  // flat dispatch id -> XCD-chunked remap (nwg = 4224 = 8*528, bijective):
  // XCD k owns logical ids [k*528, (k+1)*528) = exactly batch n=k; within a
  // batch, mt varies fastest so 12 consecutive blocks share one B s-tile.
  const int flat = blockIdx.x + NMT * (blockIdx.y + NST * blockIdx.z);
  const int swz  = (flat & 7) * (NMT * NST) + (flat >> 3);
  const int mt   = swz % NMT;
  const int st   = (swz / NMT) % NST;
  const int n    = swz / (NMT * NST);

  const int tid = threadIdx.x;
  const int lane = tid & 63;
  const int w    = tid >> 6;    // 0..3
  const int wr = w >> 1, wc = w & 1;
  const int l15 = lane & 15, l4 = lane >> 4;

  __shared__ unsigned short sA[2][128 * 64];  // 2 x 16 KB
  __shared__ unsigned short sB[2][128 * 64];  // 2 x 16 KB

  const int slab = st / 11;
  const int lt   = st - slab * 11;
  const unsigned short* gA = xq + ((size_t)n * MQP + (size_t)mt * 128) * DDIM;
  const unsigned short* gB =
      xs + ((size_t)(n * 4 + slab) * SCP + (size_t)lt * 128) * DDIM;

  // staging: 16 chunks of 1 KB (8 rows each); wave w stages chunks w*4..+3.
  // lane covers row c*8+(lane>>3), 16B slot (lane&7); source pre-swizzled by
  // (row&7); LDS dest linear => involution matches the XOR read below.
  int soff[4], ldso[4];
  #pragma unroll
  for (int i = 0; i < 4; ++i) {
    int c = w * 4 + i;
    int r = c * 8 + (lane >> 3);
    soff[i] = r * DDIM + (((lane & 7) ^ (r & 7)) << 3);
    ldso[i] = c * 512;
  }

  // fragment read byte offsets (swizzled)
  int aoff[4][2], boff[4][2];
  #pragma unroll
  for (int mf = 0; mf < 4; ++mf)
    #pragma unroll
    for (int kh = 0; kh < 2; ++kh) {
      int rowA = wr * 64 + mf * 16 + l15;
      aoff[mf][kh] = rowA * 128 + ((kh * 64 + l4 * 16) ^ ((rowA & 7) << 4));
      int rowB = wc * 64 + mf * 16 + l15;
      boff[mf][kh] = rowB * 128 + ((kh * 64 + l4 * 16) ^ ((rowB & 7) << 4));
    }

  f32x4 acc[4][4];
  {
    f32x4 zz = {0.f, 0.f, 0.f, 0.f};
    #pragma unroll
    for (int a = 0; a < 4; ++a)
      #pragma unroll
      for (int b = 0; b < 4; ++b) acc[a][b] = zz;
  }

  // prologue: stage kt=0 into buffer 0
  #pragma unroll
  for (int i = 0; i < 4; ++i) GLOAD_LDS16(gA + soff[i], sA[0] + ldso[i]);
  #pragma unroll
  for (int i = 0; i < 4; ++i) GLOAD_LDS16(gB + soff[i], sB[0] + ldso[i]);
  VMCNT0;
  BARRIER;

  for (int kt = 0; kt < 12; ++kt) {
    const unsigned short* Ab = sA[kt & 1];
    const unsigned short* Bb = sB[kt & 1];
    unsigned short* An = sA[(kt & 1) ^ 1];
    unsigned short* Bn = sB[(kt & 1) ^ 1];
    const bool issue = (kt < 11);

    if (issue) {  // prefetch kt+1 into the other buffer (read at kt-1, safe)
      const unsigned short* ga = gA + (kt + 1) * 64;
      const unsigned short* gb = gB + (kt + 1) * 64;
      #pragma unroll
      for (int i = 0; i < 4; ++i) GLOAD_LDS16(ga + soff[i], An + ldso[i]);
      #pragma unroll
      for (int i = 0; i < 4; ++i) GLOAD_LDS16(gb + soff[i], Bn + ldso[i]);
    }

    bf16x8 af[4][2], bfr[4][2];
    #pragma unroll
    for (int mf = 0; mf < 4; ++mf)
      #pragma unroll
      for (int kh = 0; kh < 2; ++kh) {
        af[mf][kh]  = *reinterpret_cast<const bf16x8*>(
            reinterpret_cast<const char*>(Ab) + aoff[mf][kh]);
        bfr[mf][kh] = *reinterpret_cast<const bf16x8*>(
            reinterpret_cast<const char*>(Bb) + boff[mf][kh]);
      }

    __builtin_amdgcn_s_setprio(1);
    #pragma unroll
    for (int mf = 0; mf < 4; ++mf)
      #pragma unroll
      for (int nf = 0; nf < 4; ++nf)
        #pragma unroll
        for (int kh = 0; kh < 2; ++kh)
          acc[mf][nf] = __builtin_amdgcn_mfma_f32_16x16x32_bf16(
              af[mf][kh], bfr[nf][kh], acc[mf][nf], 0, 0, 0);
    __builtin_amdgcn_s_setprio(0);

    if (issue) VMCNT0;  // drain next-buffer stage (issued one full kt ago)
    BARRIER;
  }

  // ---- epilogue: masked running max, butterfly, cross-wave combine
  float rmax[4][4];
  #pragma unroll
  for (int a = 0; a < 4; ++a)
    #pragma unroll
    for (int b = 0; b < 4; ++b) rmax[a][b] = -1e30f;

  #pragma unroll
  for (int nf = 0; nf < 4; ++nf) {
    int col = lt * 128 + wc * 64 + nf * 16 + l15;
    if (col < SCV) {
      #pragma unroll
      for (int mf = 0; mf < 4; ++mf)
        #pragma unroll
        for (int j = 0; j < 4; ++j)
          rmax[mf][j] = fmaxf(rmax[mf][j], acc[mf][nf][j]);
    }
  }

  #pragma unroll
  for (int msk = 1; msk < 16; msk <<= 1)
    #pragma unroll
    for (int mf = 0; mf < 4; ++mf)
      #pragma unroll
      for (int j = 0; j < 4; ++j)
        rmax[mf][j] = fmaxf(rmax[mf][j], __shfl_xor(rmax[mf][j], msk));

  __syncthreads();
  float* buf = reinterpret_cast<float*>(&sA[0][0]);  // 2*128 floats
  if (l15 == 0) {
    #pragma unroll
    for (int mf = 0; mf < 4; ++mf)
      #pragma unroll
      for (int j = 0; j < 4; ++j) {
        int r = wr * 64 + mf * 16 + l4 * 4 + j;
        buf[wc * 128 + r] = rmax[mf][j];
      }
  }
  __syncthreads();
  if (tid < 128) {
    float v = fmaxf(buf[tid], buf[128 + tid]);
    part[((size_t)n * NST + st) * MQP + (size_t)mt * 128 + tid] = v;
  }
}

extern "C" __global__ void finalize_kernel(const float* __restrict__ part,
                                           float* __restrict__ out) {
  int i = blockIdx.x * 256 + threadIdx.x;
  if (i >= NB * SCV) return;
  int n = i / SCV, q = i - n * SCV;
  const float* p = part + (size_t)n * NST * MQP + q;
  float m = p[0];
  #pragma unroll 4
  for (int g = 1; g < NST; ++g) m = fmaxf(m, p[(size_t)g * MQP]);
  out[i] = 1.0f - m;
}

extern "C" void kernel_launch(void* const* d_in, const int* in_sizes, int n_in,
                              void* d_out, int out_size, void* d_ws, size_t ws_size,
                              hipStream_t stream) {
  const float* q_feats = (const float*)d_in[0];  // (3, 8, 1370, 768) f32
  const float* s_feats = (const float*)d_in[1];  // (3, 32, 1370, 768) f32
  float* out = (float*)d_out;                    // (8, 1, 37, 37) f32

  char* ws = (char*)d_ws;
  const size_t xq_bytes = (size_t)NB * MQP * DDIM * 2;     // 18,874,368
  const size_t xs_bytes = (size_t)NSLAB * SCP * DDIM * 2;  // 69,206,016
  unsigned short* xq = (unsigned short*)ws;
  unsigned short* xs = (unsigned short*)(ws + xq_bytes);
  float* part        = (float*)(ws + xq_bytes + xs_bytes); // 8*44*1536 floats

  prep_kernel<<<dim3(MQP, NB), 192, 0, stream>>>(
      q_feats, xq, (size_t)NB * T_TOK * DDIM);
  prep_kernel<<<dim3(SCP, NSLAB), 192, 0, stream>>>(
      s_feats, xs, (size_t)NSLAB * T_TOK * DDIM);
  simmax_kernel<<<dim3(NMT, NST, NB), 256, 0, stream>>>(xq, xs, part);
  finalize_kernel<<<dim3((NB * SCV + 255) / 256), 256, 0, stream>>>(part, out);
}

// Round 5
// 249.035 us; speedup vs baseline: 1.2587x; 1.0292x over previous
//
#include <hip/hip_runtime.h>
#include <hip/hip_bf16.h>

typedef __attribute__((ext_vector_type(8))) short bf16x8;
typedef __attribute__((ext_vector_type(4))) float f32x4;

#define T_TOK 1370
#define DDIM  768
#define SCV   1369   // valid tokens per slab
#define SCP   1408   // s slab padded rows (11*128)
#define MQP   1536   // q padded rows (6*256)
#define NB    8
#define NSLAB 32
#define NST   44     // s tiles of 128 (4 slabs * 11)
#define NMT   6      // m tiles of 256

#define MEMFENCE asm volatile("" ::: "memory")
#define BARRIER  do { __builtin_amdgcn_s_barrier(); MEMFENCE; } while (0)

__device__ __forceinline__ unsigned short f2bf(float x) {
  union { __hip_bfloat16 h; unsigned short u; } cv;
  cv.h = __float2bfloat16(x);
  return cv.u;
}

#define GLOAD_LDS16(g, l)                                                     \
  __builtin_amdgcn_global_load_lds(                                           \
      (const __attribute__((address_space(1))) unsigned int*)(g),             \
      (__attribute__((address_space(3))) unsigned int*)(l), 16, 0, 0)

// One block per output row: mean over 3 layers -> l2norm -> bf16 store.
// dst layout: [slabs][pad][768] bf16, rows >= 1369 zeroed. pad via gridDim.x.
extern "C" __global__ __launch_bounds__(192) void prep_kernel(
    const float* __restrict__ src, unsigned short* __restrict__ dst,
    size_t lstride)
{
  const int row  = blockIdx.x;
  const int slab = blockIdx.y;
  const int t    = threadIdx.x;  // 0..191, each owns one float4 (768 = 192*4)
  unsigned short* drow = dst + ((size_t)slab * gridDim.x + row) * DDIM;
  if (row >= SCV) {
    ushort4 z; z.x = z.y = z.z = z.w = 0;
    reinterpret_cast<ushort4*>(drow)[t] = z;
    return;
  }
  const float* base = src + ((size_t)slab * T_TOK + row + 1) * DDIM;
  float4 a = reinterpret_cast<const float4*>(base)[t];
  float4 b = reinterpret_cast<const float4*>(base + lstride)[t];
  float4 c = reinterpret_cast<const float4*>(base + 2 * lstride)[t];
  const float k3 = 1.0f / 3.0f;
  float4 m;
  m.x = (a.x + b.x + c.x) * k3;
  m.y = (a.y + b.y + c.y) * k3;
  m.z = (a.z + b.z + c.z) * k3;
  m.w = (a.w + b.w + c.w) * k3;
  float ss = m.x * m.x + m.y * m.y + m.z * m.z + m.w * m.w;
  #pragma unroll
  for (int d = 1; d < 64; d <<= 1) ss += __shfl_xor(ss, d);
  __shared__ float wsum[3];
  if ((t & 63) == 0) wsum[t >> 6] = ss;
  __syncthreads();
  float tot = wsum[0] + wsum[1] + wsum[2];
  float rn = 1.0f / fmaxf(sqrtf(tot), 1e-12f);
  ushort4 o;
  o.x = f2bf(m.x * rn); o.y = f2bf(m.y * rn);
  o.z = f2bf(m.z * rn); o.w = f2bf(m.w * rn);
  reinterpret_cast<ushort4*>(drow)[t] = o;
}

// 256x128 tile GEMM-with-running-max; ring-3 LDS, counted vmcnt(6) pipeline
// (loads stay in flight across barriers, never drained to 0 in the loop).
// 512 thr (8 waves, 4M x 2N), 1 block/CU. part: [8][44][1536] float.
extern "C" __global__ __launch_bounds__(512, 2) void simmax_kernel(
    const unsigned short* __restrict__ xq,
    const unsigned short* __restrict__ xs,
    float* __restrict__ part)
{
  // XCD-chunked bijective remap: nwg = 2112 = 8*264; XCD k owns batch n=k.
  const int flat = blockIdx.x + NMT * (blockIdx.y + NST * blockIdx.z);
  const int swz  = (flat & 7) * (NMT * NST) + (flat >> 3);
  const int mt   = swz % NMT;
  const int st   = (swz / NMT) % NST;
  const int n    = swz / (NMT * NST);

  const int tid = threadIdx.x;
  const int lane = tid & 63;
  const int w    = tid >> 6;    // 0..7
  const int wr = w >> 1;        // 0..3 (64-row band of 256)
  const int wc = w & 1;         // 0..1 (64-col half of 128)
  const int l15 = lane & 15, l4 = lane >> 4;

  // ring buffer: [3] x (A 256x64 | B 128x64) bf16 = 3 x 48 KB = 144 KB
  __shared__ unsigned short ring[3][24576];

  const int slab = st / 11;
  const int lt   = st - slab * 11;
  const unsigned short* gA = xq + ((size_t)n * MQP + (size_t)mt * 256) * DDIM;
  const unsigned short* gB =
      xs + ((size_t)(n * 4 + slab) * SCP + (size_t)lt * 128) * DDIM;

  // staging: A = 32 chunks of 1KB (8 rows), wave w owns chunks w*4..+3;
  //          B = 16 chunks, wave w owns w*2..+1. 6 loads/wave per K-step.
  // lane -> row c*8+(lane>>3), 16B slot (lane&7); source pre-swizzled by
  // (row&7), LDS dest linear => involution matches the XOR read below.
  int aoffg[4], aldso[4], boffg[2], bldso[2];
  #pragma unroll
  for (int i = 0; i < 4; ++i) {
    int c = w * 4 + i;
    int r = c * 8 + (lane >> 3);
    aoffg[i] = r * DDIM + (((lane & 7) ^ (r & 7)) << 3);
    aldso[i] = c * 512;
  }
  #pragma unroll
  for (int i = 0; i < 2; ++i) {
    int c = w * 2 + i;
    int r = c * 8 + (lane >> 3);
    boffg[i] = r * DDIM + (((lane & 7) ^ (r & 7)) << 3);
    bldso[i] = 16384 + c * 512;   // B region starts at 32 KB
  }

  // fragment read byte offsets (swizzled)
  int aoff[4][2], boff[4][2];
  #pragma unroll
  for (int mf = 0; mf < 4; ++mf)
    #pragma unroll
    for (int kh = 0; kh < 2; ++kh) {
      int rowA = wr * 64 + mf * 16 + l15;
      aoff[mf][kh] = rowA * 128 + ((kh * 64 + l4 * 16) ^ ((rowA & 7) << 4));
      int rowB = wc * 64 + mf * 16 + l15;
      boff[mf][kh] = 32768 + rowB * 128 +
                     ((kh * 64 + l4 * 16) ^ ((rowB & 7) << 4));
    }

  f32x4 acc[4][4];
  {
    f32x4 zz = {0.f, 0.f, 0.f, 0.f};
    #pragma unroll
    for (int a = 0; a < 4; ++a)
      #pragma unroll
      for (int b = 0; b < 4; ++b) acc[a][b] = zz;
  }

  #define ISSUE(KT, RB)                                                       \
    do {                                                                      \
      const unsigned short* ga_ = gA + (KT) * 64;                             \
      const unsigned short* gb_ = gB + (KT) * 64;                             \
      unsigned short* lb_ = ring[RB];                                         \
      _Pragma("unroll") for (int i = 0; i < 4; ++i)                           \
        GLOAD_LDS16(ga_ + aoffg[i], lb_ + aldso[i]);                          \
      _Pragma("unroll") for (int i = 0; i < 2; ++i)                           \
        GLOAD_LDS16(gb_ + boffg[i], lb_ + bldso[i]);                          \
    } while (0)

  // prologue: fill pipeline 2 deep
  ISSUE(0, 0);
  ISSUE(1, 1);
  asm volatile("s_waitcnt vmcnt(6)" ::: "memory");  // kt0 landed, kt1 flying
  BARRIER;

  for (int kt = 0; kt < 12; ++kt) {
    if (kt + 2 < 12) ISSUE(kt + 2, (kt + 2) % 3);

    const unsigned short* Cb = ring[kt % 3];
    bf16x8 af[4][2], bfr[4][2];
    #pragma unroll
    for (int mf = 0; mf < 4; ++mf)
      #pragma unroll
      for (int kh = 0; kh < 2; ++kh) {
        af[mf][kh]  = *reinterpret_cast<const bf16x8*>(
            reinterpret_cast<const char*>(Cb) + aoff[mf][kh]);
        bfr[mf][kh] = *reinterpret_cast<const bf16x8*>(
            reinterpret_cast<const char*>(Cb) + boff[mf][kh]);
      }

    __builtin_amdgcn_s_setprio(1);
    #pragma unroll
    for (int mf = 0; mf < 4; ++mf)
      #pragma unroll
      for (int nf = 0; nf < 4; ++nf)
        #pragma unroll
        for (int kh = 0; kh < 2; ++kh)
          acc[mf][nf] = __builtin_amdgcn_mfma_f32_16x16x32_bf16(
              af[mf][kh], bfr[nf][kh], acc[mf][nf], 0, 0, 0);
    __builtin_amdgcn_s_setprio(0);

    // wait for NEXT buffer (issued a full K-step ago); keep kt+2's 6 in flight
    if (kt < 10)      asm volatile("s_waitcnt vmcnt(6)" ::: "memory");
    else if (kt == 10) asm volatile("s_waitcnt vmcnt(0)" ::: "memory");
    if (kt < 11) BARRIER;
  }

  // ---- epilogue: masked running max, butterfly, cross-wave combine
  float rmax[4][4];
  #pragma unroll
  for (int a = 0; a < 4; ++a)
    #pragma unroll
    for (int b = 0; b < 4; ++b) rmax[a][b] = -1e30f;

  #pragma unroll
  for (int nf = 0; nf < 4; ++nf) {
    int col = lt * 128 + wc * 64 + nf * 16 + l15;
    if (col < SCV) {
      #pragma unroll
      for (int mf = 0; mf < 4; ++mf)
        #pragma unroll
        for (int j = 0; j < 4; ++j)
          rmax[mf][j] = fmaxf(rmax[mf][j], acc[mf][nf][j]);
    }
  }

  #pragma unroll
  for (int msk = 1; msk < 16; msk <<= 1)
    #pragma unroll
    for (int mf = 0; mf < 4; ++mf)
      #pragma unroll
      for (int j = 0; j < 4; ++j)
        rmax[mf][j] = fmaxf(rmax[mf][j], __shfl_xor(rmax[mf][j], msk));

  __syncthreads();
  float* buf = reinterpret_cast<float*>(&ring[0][0]);  // 2 x 256 floats
  if (l15 == 0) {
    #pragma unroll
    for (int mf = 0; mf < 4; ++mf)
      #pragma unroll
      for (int j = 0; j < 4; ++j) {
        int r = wr * 64 + mf * 16 + l4 * 4 + j;   // 0..255
        buf[wc * 256 + r] = rmax[mf][j];
      }
  }
  __syncthreads();
  if (tid < 256) {
    float v = fmaxf(buf[tid], buf[256 + tid]);
    part[((size_t)n * NST + st) * MQP + (size_t)mt * 256 + tid] = v;
  }
}

extern "C" __global__ void finalize_kernel(const float* __restrict__ part,
                                           float* __restrict__ out) {
  int i = blockIdx.x * 256 + threadIdx.x;
  if (i >= NB * SCV) return;
  int n = i / SCV, q = i - n * SCV;
  const float* p = part + (size_t)n * NST * MQP + q;
  float m = p[0];
  #pragma unroll 4
  for (int g = 1; g < NST; ++g) m = fmaxf(m, p[(size_t)g * MQP]);
  out[i] = 1.0f - m;
}

extern "C" void kernel_launch(void* const* d_in, const int* in_sizes, int n_in,
                              void* d_out, int out_size, void* d_ws, size_t ws_size,
                              hipStream_t stream) {
  const float* q_feats = (const float*)d_in[0];  // (3, 8, 1370, 768) f32
  const float* s_feats = (const float*)d_in[1];  // (3, 32, 1370, 768) f32
  float* out = (float*)d_out;                    // (8, 1, 37, 37) f32

  char* ws = (char*)d_ws;
  const size_t xq_bytes = (size_t)NB * MQP * DDIM * 2;     // 18,874,368
  const size_t xs_bytes = (size_t)NSLAB * SCP * DDIM * 2;  // 69,206,016
  unsigned short* xq = (unsigned short*)ws;
  unsigned short* xs = (unsigned short*)(ws + xq_bytes);
  float* part        = (float*)(ws + xq_bytes + xs_bytes); // 8*44*1536 floats

  prep_kernel<<<dim3(MQP, NB), 192, 0, stream>>>(
      q_feats, xq, (size_t)NB * T_TOK * DDIM);
  prep_kernel<<<dim3(SCP, NSLAB), 192, 0, stream>>>(
      s_feats, xs, (size_t)NSLAB * T_TOK * DDIM);
  simmax_kernel<<<dim3(NMT, NST, NB), 512, 0, stream>>>(xq, xs, part);
  finalize_kernel<<<dim3((NB * SCV + 255) / 256), 256, 0, stream>>>(part, out);
}

// Round 6
// 242.538 us; speedup vs baseline: 1.2924x; 1.0268x over previous
//
#include <hip/hip_runtime.h>
#include <hip/hip_bf16.h>

typedef __attribute__((ext_vector_type(8))) short bf16x8;
typedef __attribute__((ext_vector_type(4))) float f32x4;

#define T_TOK 1370
#define DDIM  768
#define SCV   1369   // valid tokens per slab
#define SCP   1408   // s slab padded rows (11*128)
#define MQP   1536   // q padded rows (6*256)
#define NB    8
#define NSLAB 32
#define NST   44     // s tiles of 128 (4 slabs * 11)
#define NMT   6      // m tiles of 256

#define MEMFENCE asm volatile("" ::: "memory")
#define BARRIER  do { __builtin_amdgcn_s_barrier(); MEMFENCE; } while (0)

__device__ __forceinline__ unsigned short f2bf(float x) {
  union { __hip_bfloat16 h; unsigned short u; } cv;
  cv.h = __float2bfloat16(x);
  return cv.u;
}

#define GLOAD_LDS16(g, l)                                                     \
  __builtin_amdgcn_global_load_lds(                                           \
      (const __attribute__((address_space(1))) unsigned int*)(g),             \
      (__attribute__((address_space(3))) unsigned int*)(l), 16, 0, 0)

// One block per output row: mean over 3 layers -> l2norm -> bf16 store.
// dst layout: [slabs][pad][768] bf16, rows >= 1369 zeroed. pad via gridDim.x.
extern "C" __global__ __launch_bounds__(192) void prep_kernel(
    const float* __restrict__ src, unsigned short* __restrict__ dst,
    size_t lstride)
{
  const int row  = blockIdx.x;
  const int slab = blockIdx.y;
  const int t    = threadIdx.x;  // 0..191, each owns one float4 (768 = 192*4)
  unsigned short* drow = dst + ((size_t)slab * gridDim.x + row) * DDIM;
  if (row >= SCV) {
    ushort4 z; z.x = z.y = z.z = z.w = 0;
    reinterpret_cast<ushort4*>(drow)[t] = z;
    return;
  }
  const float* base = src + ((size_t)slab * T_TOK + row + 1) * DDIM;
  float4 a = reinterpret_cast<const float4*>(base)[t];
  float4 b = reinterpret_cast<const float4*>(base + lstride)[t];
  float4 c = reinterpret_cast<const float4*>(base + 2 * lstride)[t];
  const float k3 = 1.0f / 3.0f;
  float4 m;
  m.x = (a.x + b.x + c.x) * k3;
  m.y = (a.y + b.y + c.y) * k3;
  m.z = (a.z + b.z + c.z) * k3;
  m.w = (a.w + b.w + c.w) * k3;
  float ss = m.x * m.x + m.y * m.y + m.z * m.z + m.w * m.w;
  #pragma unroll
  for (int d = 1; d < 64; d <<= 1) ss += __shfl_xor(ss, d);
  __shared__ float wsum[3];
  if ((t & 63) == 0) wsum[t >> 6] = ss;
  __syncthreads();
  float tot = wsum[0] + wsum[1] + wsum[2];
  float rn = 1.0f / fmaxf(sqrtf(tot), 1e-12f);
  ushort4 o;
  o.x = f2bf(m.x * rn); o.y = f2bf(m.y * rn);
  o.z = f2bf(m.z * rn); o.w = f2bf(m.w * rn);
  reinterpret_cast<ushort4*>(drow)[t] = o;
}

// 256x128 tile, BK=32, 4 waves (2Mx2N, per-wave 128x64), ring-3 LDS,
// counted vmcnt(6), 2 blocks/CU. part: [8][44][1536] float.
extern "C" __global__ __launch_bounds__(256, 2) void simmax_kernel(
    const unsigned short* __restrict__ xq,
    const unsigned short* __restrict__ xs,
    float* __restrict__ part)
{
  // XCD-chunked bijective remap: nwg = 2112 = 8*264; XCD k owns batch n=k,
  // mt varies fastest so 6 consecutive blocks share one B s-tile.
  const int flat = blockIdx.x + NMT * (blockIdx.y + NST * blockIdx.z);
  const int swz  = (flat & 7) * (NMT * NST) + (flat >> 3);
  const int mt   = swz % NMT;
  const int st   = (swz / NMT) % NST;
  const int n    = swz / (NMT * NST);

  const int tid = threadIdx.x;
  const int lane = tid & 63;
  const int w    = tid >> 6;    // 0..3
  const int wr = w >> 1;        // 0..1 (128-row band of 256)
  const int wc = w & 1;         // 0..1 (64-col half of 128)
  const int l15 = lane & 15, l4 = lane >> 4;

  // ring: [3] x (A 256x32 | B 128x32) bf16 = 3 x 24 KB = 72 KB
  __shared__ unsigned short ring[3][12288];

  const int slab = st / 11;
  const int lt   = st - slab * 11;
  const unsigned short* gA = xq + ((size_t)n * MQP + (size_t)mt * 256) * DDIM;
  const unsigned short* gB =
      xs + ((size_t)(n * 4 + slab) * SCP + (size_t)lt * 128) * DDIM;

  // staging: 1-KB chunks = 16 rows x 64 B. A = 16 chunks (wave owns w*4..+3),
  // B = 8 chunks (wave owns w*2..+1). lane -> row c*16+(lane>>2), 16-B slot
  // (lane&3). Source pre-swizzled slot^(row&3); LDS dest linear; read XORs
  // the same involution => zero-conflict reads (8 accesses/bank uniform).
  int aoffg[4], aldso[4], boffg[2], bldso[2];
  #pragma unroll
  for (int i = 0; i < 4; ++i) {
    int c = w * 4 + i;
    int r = c * 16 + (lane >> 2);
    aoffg[i] = r * DDIM + (((lane & 3) ^ (r & 3)) << 3);
    aldso[i] = c * 512;
  }
  #pragma unroll
  for (int i = 0; i < 2; ++i) {
    int c = w * 2 + i;
    int r = c * 16 + (lane >> 2);
    boffg[i] = r * DDIM + (((lane & 3) ^ (r & 3)) << 3);
    bldso[i] = 8192 + c * 512;   // B region starts at 16 KB
  }

  // fragment read byte offsets: row*64 + ((l4*16) ^ ((row&3)<<4));
  // row&3 == l15&3 for every fragment row.
  const int kxor = (l4 * 16) ^ ((l15 & 3) << 4);
  int aoff[8], boff[4];
  #pragma unroll
  for (int mf = 0; mf < 8; ++mf)
    aoff[mf] = (wr * 128 + mf * 16 + l15) * 64 + kxor;
  #pragma unroll
  for (int nf = 0; nf < 4; ++nf)
    boff[nf] = 16384 + (wc * 64 + nf * 16 + l15) * 64 + kxor;

  f32x4 acc[8][4];
  {
    f32x4 zz = {0.f, 0.f, 0.f, 0.f};
    #pragma unroll
    for (int a = 0; a < 8; ++a)
      #pragma unroll
      for (int b = 0; b < 4; ++b) acc[a][b] = zz;
  }

  #define ISSUE(KT, RB)                                                       \
    do {                                                                      \
      const unsigned short* ga_ = gA + (KT) * 32;                             \
      const unsigned short* gb_ = gB + (KT) * 32;                             \
      unsigned short* lb_ = ring[RB];                                         \
      _Pragma("unroll") for (int i = 0; i < 4; ++i)                           \
        GLOAD_LDS16(ga_ + aoffg[i], lb_ + aldso[i]);                          \
      _Pragma("unroll") for (int i = 0; i < 2; ++i)                           \
        GLOAD_LDS16(gb_ + boffg[i], lb_ + bldso[i]);                          \
    } while (0)

  // prologue: fill pipeline 2 deep
  ISSUE(0, 0);
  ISSUE(1, 1);
  asm volatile("s_waitcnt vmcnt(6)" ::: "memory");  // kt0 landed, kt1 flying
  BARRIER;

  for (int kt = 0; kt < 24; ++kt) {
    if (kt + 2 < 24) ISSUE(kt + 2, (kt + 2) % 3);

    const char* Cb = reinterpret_cast<const char*>(ring[kt % 3]);
    bf16x8 bfr[4], af[8];
    #pragma unroll
    for (int nf = 0; nf < 4; ++nf)
      bfr[nf] = *reinterpret_cast<const bf16x8*>(Cb + boff[nf]);
    #pragma unroll
    for (int mf = 0; mf < 8; ++mf)
      af[mf] = *reinterpret_cast<const bf16x8*>(Cb + aoff[mf]);

    __builtin_amdgcn_s_setprio(1);
    #pragma unroll
    for (int mf = 0; mf < 8; ++mf)
      #pragma unroll
      for (int nf = 0; nf < 4; ++nf)
        acc[mf][nf] = __builtin_amdgcn_mfma_f32_16x16x32_bf16(
            af[mf], bfr[nf], acc[mf][nf], 0, 0, 0);
    __builtin_amdgcn_s_setprio(0);

    // wait for NEXT buffer's batch (issued a full K-step ago); keep the
    // just-issued 6 in flight across the barrier.
    if (kt < 22)       asm volatile("s_waitcnt vmcnt(6)" ::: "memory");
    else if (kt == 22) asm volatile("s_waitcnt vmcnt(0)" ::: "memory");
    if (kt < 23) BARRIER;
  }

  // ---- epilogue: masked running max, butterfly, cross-wave combine
  float rmax[8][4];
  #pragma unroll
  for (int a = 0; a < 8; ++a)
    #pragma unroll
    for (int b = 0; b < 4; ++b) rmax[a][b] = -1e30f;

  #pragma unroll
  for (int nf = 0; nf < 4; ++nf) {
    int col = lt * 128 + wc * 64 + nf * 16 + l15;
    if (col < SCV) {
      #pragma unroll
      for (int mf = 0; mf < 8; ++mf)
        #pragma unroll
        for (int j = 0; j < 4; ++j)
          rmax[mf][j] = fmaxf(rmax[mf][j], acc[mf][nf][j]);
    }
  }

  #pragma unroll
  for (int msk = 1; msk < 16; msk <<= 1)
    #pragma unroll
    for (int mf = 0; mf < 8; ++mf)
      #pragma unroll
      for (int j = 0; j < 4; ++j)
        rmax[mf][j] = fmaxf(rmax[mf][j], __shfl_xor(rmax[mf][j], msk));

  __syncthreads();
  float* buf = reinterpret_cast<float*>(&ring[0][0]);  // 2 x 256 floats
  if (l15 == 0) {
    #pragma unroll
    for (int mf = 0; mf < 8; ++mf)
      #pragma unroll
      for (int j = 0; j < 4; ++j) {
        int r = wr * 128 + mf * 16 + l4 * 4 + j;   // 0..255
        buf[wc * 256 + r] = rmax[mf][j];
      }
  }
  __syncthreads();
  if (tid < 256) {
    float v = fmaxf(buf[tid], buf[256 + tid]);
    part[((size_t)n * NST + st) * MQP + (size_t)mt * 256 + tid] = v;
  }
}

extern "C" __global__ void finalize_kernel(const float* __restrict__ part,
                                           float* __restrict__ out) {
  int i = blockIdx.x * 256 + threadIdx.x;
  if (i >= NB * SCV) return;
  int n = i / SCV, q = i - n * SCV;
  const float* p = part + (size_t)n * NST * MQP + q;
  float m = p[0];
  #pragma unroll 4
  for (int g = 1; g < NST; ++g) m = fmaxf(m, p[(size_t)g * MQP]);
  out[i] = 1.0f - m;
}

extern "C" void kernel_launch(void* const* d_in, const int* in_sizes, int n_in,
                              void* d_out, int out_size, void* d_ws, size_t ws_size,
                              hipStream_t stream) {
  const float* q_feats = (const float*)d_in[0];  // (3, 8, 1370, 768) f32
  const float* s_feats = (const float*)d_in[1];  // (3, 32, 1370, 768) f32
  float* out = (float*)d_out;                    // (8, 1, 37, 37) f32

  char* ws = (char*)d_ws;
  const size_t xq_bytes = (size_t)NB * MQP * DDIM * 2;     // 18,874,368
  const size_t xs_bytes = (size_t)NSLAB * SCP * DDIM * 2;  // 69,206,016
  unsigned short* xq = (unsigned short*)ws;
  unsigned short* xs = (unsigned short*)(ws + xq_bytes);
  float* part        = (float*)(ws + xq_bytes + xs_bytes); // 8*44*1536 floats

  prep_kernel<<<dim3(MQP, NB), 192, 0, stream>>>(
      q_feats, xq, (size_t)NB * T_TOK * DDIM);
  prep_kernel<<<dim3(SCP, NSLAB), 192, 0, stream>>>(
      s_feats, xs, (size_t)NSLAB * T_TOK * DDIM);
  simmax_kernel<<<dim3(NMT, NST, NB), 256, 0, stream>>>(xq, xs, part);
  finalize_kernel<<<dim3((NB * SCV + 255) / 256), 256, 0, stream>>>(part, out);
}